// Round 1
// baseline (92.277 us; speedup 1.0000x reference)
//
#include <hip/hip_runtime.h>
#include <math.h>

typedef unsigned int uint32;
typedef unsigned short u16;
typedef __bf16 bf16x8 __attribute__((ext_vector_type(8)));
typedef float f32x16 __attribute__((ext_vector_type(16)));

#define BROWS 8192
#define WDIM 256
#define NT 3             // 128x128 tile pairs: t0=(0,0), t1=(0,1), t2=(1,1)
#define CHUNKS 64        // 64 * 128 rows = 8192
#define TILE_ELEMS 16384
#define GRID_BLKS (NT * CHUNKS)   // 192 blocks, all co-resident on 256 CUs

// ws float layout:
// [0 .. 16383]   colsum_part[64 chunks][256] (plain stores by t1 blocks)
// [16384]        lossacc  (zeroed by block (0,0) before the grid barrier)
// [16385]        done u32
// [16640 .. ]    partials bf16: NT*CHUNKS*TILE_ELEMS u16 (6.3 MB)
#define WS_LOSS 16384
#define WS_DONE 16385
#define WS_PART 16640

// Grid-barrier arrive counter. Lives in __device__ (ws is poisoned every
// iteration). Monotonic: grows by exactly GRID_BLKS per launch, so the
// target is "next multiple of GRID_BLKS" — graph replays need no reset.
__device__ unsigned g_bar1 = 0;

__device__ __forceinline__ uint32 pack2bf(float lo, float hi) {
    uint32 a = __float_as_uint(lo), b = __float_as_uint(hi);
    a = (a + 0x7FFFu + ((a >> 16) & 1u)) >> 16;   // RNE fp32->bf16
    b = (b + 0x7FFFu + ((b >> 16) & 1u)) >> 16;
    return (a & 0xFFFFu) | (b << 16);
}
__device__ __forceinline__ u16 f2bf(float x) {
    uint32 a = __float_as_uint(x);
    return (u16)((a + 0x7FFFu + ((a >> 16) & 1u)) >> 16);
}
__device__ __forceinline__ float bflo(uint32 v) { return __uint_as_float(v << 16); }
__device__ __forceinline__ float bfhi(uint32 v) { return __uint_as_float(v & 0xFFFF0000u); }

// LDS layout: U[col][krp] (krp = k/2, 64 dwords per col), 16B-group XOR swizzle.
__device__ __forceinline__ int uswz(int col, int krp) {
    return col * 64 + ((((krp >> 2) ^ (col & 15)) << 2) | (krp & 3));
}

// Single fused kernel: phase A = cast+MFMA gram (+colsum), device-scope grid
// barrier, phase B = finalize loss + sqrt. One dispatch instead of two.
__global__ __launch_bounds__(256)
void corr_fused(const float* __restrict__ E, float* __restrict__ ws,
                float* __restrict__ out) {
    __shared__ uint32 U[WDIM * 64];            // 64 KB
    __shared__ float red[4];
    const int t = blockIdx.x, c = blockIdx.y;
    const int tid = threadIdx.x;
    const int ncg = (t == 1) ? 4 : 2;          // 64-col groups held in U
    const int gcol0 = (t == 2) ? 128 : 0;      // global col of U local col 0
    const int row0 = c * 128;
    const int c4 = tid & 15, rp = tid >> 4;

    // Zero lossacc+done. Ordered before all phase-B uses by the grid barrier.
    if (t == 0 && c == 0 && tid < 2) ws[WS_LOSS + tid] = 0.0f;

    // ---------------- phase A: load + cast to LDS ----------------
    for (int cg = 0; cg < ncg; ++cg) {
        const float* Eb = E + (size_t)row0 * WDIM + gcol0 + cg * 64;
        float4 fa[4], fb[4];
        #pragma unroll
        for (int p = 0; p < 4; ++p) {          // rowpairs rp+16p -> rows 2*,2*+1
            const int r0 = 2 * (rp + 16 * p);
            fa[p] = *(const float4*)(Eb + (size_t)r0 * WDIM + c4 * 4);
            fb[p] = *(const float4*)(Eb + (size_t)(r0 + 1) * WDIM + c4 * 4);
        }
        #pragma unroll
        for (int p = 0; p < 4; ++p) {
            const int krp = rp + 16 * p;
            const int colb = cg * 64 + c4 * 4;
            const float av[4] = {fa[p].x, fa[p].y, fa[p].z, fa[p].w};
            const float bv[4] = {fb[p].x, fb[p].y, fb[p].z, fb[p].w};
            #pragma unroll
            for (int i = 0; i < 4; ++i)
                U[uswz(colb + i, krp)] = pack2bf(av[i], bv[i]);
        }
    }
    __syncthreads();

    if (t == 1) {                              // colsum (bf16-rounded; err ~4e-5)
        const int col = tid;                   // all 256 cols live in U here
        float s = 0.f;
        #pragma unroll
        for (int g = 0; g < 16; ++g) {
            const uint4 v = *(const uint4*)&U[col * 64 + ((g ^ (col & 15)) << 2)];
            s += bflo(v.x) + bfhi(v.x) + bflo(v.y) + bfhi(v.y)
               + bflo(v.z) + bfhi(v.z) + bflo(v.w) + bfhi(v.w);
        }
        ws[c * WDIM + col] = s;                // per-chunk slot, no init needed
    }

    // MFMA: wave w -> tile rows [32w,32w+32); local col = global - gcol0.
    const int w = tid >> 6, l = tid & 63, lm = l & 31;
    const int bBase = (t == 1) ? 128 : 0;
    const int colA = w * 32 + lm;

    f32x16 acc[4];
    #pragma unroll
    for (int n = 0; n < 4; ++n)
        #pragma unroll
        for (int r = 0; r < 16; ++r) acc[n][r] = 0.f;

    #pragma unroll
    for (int s8 = 0; s8 < 8; ++s8) {           // K = 128 = 8 steps of 16
        const int grp = 2 * s8 + (l >> 5);     // logical 16B group = k/8
        const bf16x8 a = *(const bf16x8*)&U[colA * 64 + ((grp ^ (colA & 15)) << 2)];
        #pragma unroll
        for (int n = 0; n < 4; ++n) {
            const int colB = bBase + n * 32 + lm;
            const bf16x8 b = *(const bf16x8*)&U[colB * 64 + ((grp ^ (colB & 15)) << 2)];
            acc[n] = __builtin_amdgcn_mfma_f32_32x32x16_bf16(a, b, acc[n], 0, 0, 0);
        }
    }

    // bf16 partials. C/D layout (m74/m101): col = lane&31, row = (r&3)+8*(r>>2)+4*(lane>>5)
    u16* part = (u16*)(ws + WS_PART);
    u16* dst = part + ((size_t)c * NT + t) * TILE_ELEMS;
    const int rbase = 32 * w + 4 * (l >> 5);
    #pragma unroll
    for (int n = 0; n < 4; ++n)
        #pragma unroll
        for (int r = 0; r < 16; ++r) {
            const int row = rbase + (r & 3) + 8 * (r >> 2);
            dst[row * 128 + n * 32 + lm] = f2bf(acc[n][r]);
        }

    // ---------------- device-scope grid barrier ----------------
    // Safe: 192 blocks x 64KB LDS x 4 waves are all co-resident on 256 CUs.
    __syncthreads();                           // all waves' stores issued+drained
    if (tid == 0) {
        __threadfence();                       // release: wbL2 partials/colsums
        const unsigned old = atomicAdd(&g_bar1, 1u);
        const unsigned target = old - (old % GRID_BLKS) + GRID_BLKS;
        while (atomicAdd(&g_bar1, 0u) < target) __builtin_amdgcn_s_sleep(4);
        __threadfence();                       // acquire: inv stale L1/L2
    }
    __syncthreads();

    // ---------------- phase B: finalize loss + sqrt ----------------
    const int b = c * NT + t;                  // flat block id 0..191
    float* muS = (float*)U;                    // U is dead; reuse LDS for mu
    const u16* partR = (const u16*)(ws + WS_PART);
    float* lossacc = ws + WS_LOSS;
    unsigned* done = (unsigned*)(ws + WS_DONE);

    {   // reduce the 64 per-chunk colsum slots -> mu
        float s = 0.f;
        #pragma unroll 8
        for (int cc = 0; cc < CHUNKS; ++cc) s += ws[cc * WDIM + tid];
        muS[tid] = s * (1.0f / (float)BROWS);
    }
    __syncthreads();

    const int e = b * 256 + tid;               // 0..49151
    const int tt = e >> 14, local = e & 16383;
    const int ti = (tt == 2) ? 1 : 0;
    const int tj = (tt == 0) ? 0 : 1;
    const int i = ti * 128 + (local >> 7);
    const int j = tj * 128 + (local & 127);

    float g = 0.f;
    #pragma unroll 8
    for (int cc = 0; cc < CHUNKS; ++cc)
        g += bflo((uint32)partR[((size_t)cc * NT + tt) * TILE_ELEMS + local]);

    const float diff = g * (1.0f / (float)BROWS) - muS[i] * muS[j] - ((i == j) ? 1.0f : 0.0f);
    float v = ((tt == 1) ? 2.0f : 1.0f) * diff * diff;

    #pragma unroll
    for (int o = 32; o > 0; o >>= 1) v += __shfl_down(v, o, 64);
    if ((tid & 63) == 0) red[tid >> 6] = v;
    __syncthreads();
    if (tid == 0) {
        atomicAdd(lossacc, red[0] + red[1] + red[2] + red[3]);
        __threadfence();
        const unsigned fin = atomicAdd(done, 1u);
        if (fin == GRID_BLKS - 1) {
            __threadfence();
            out[0] = sqrtf(atomicAdd(lossacc, 0.0f));  // atomic read
        }
    }
}

// ---------------------------------------------------------------------- host
extern "C" void kernel_launch(void* const* d_in, const int* in_sizes, int n_in,
                              void* d_out, int out_size, void* d_ws, size_t ws_size,
                              hipStream_t stream) {
    const float* E = (const float*)d_in[0];
    // d_in[1] (label) unused by the reference math.
    float* out = (float*)d_out;
    float* ws = (float*)d_ws;

    corr_fused<<<dim3(NT, CHUNKS), 256, 0, stream>>>(E, ws, out);
}

// Round 2
// 92.007 us; speedup vs baseline: 1.0029x; 1.0029x over previous
//
#include <hip/hip_runtime.h>
#include <math.h>

typedef unsigned int uint32;
typedef unsigned short u16;
typedef __bf16 bf16x8 __attribute__((ext_vector_type(8)));
typedef float f32x16 __attribute__((ext_vector_type(16)));

#define BROWS 8192
#define WDIM 256
#define NT 3             // 128x128 tile pairs: t0=(0,0), t1=(0,1), t2=(1,1)
#define CHUNKS 64        // 64 * 128 rows = 8192
#define TILE_ELEMS 16384
#define GRID_BLKS (NT * CHUNKS)   // 192 blocks; 64KB LDS -> 2 blocks/CU, all co-resident

// ws float layout:
// [0 .. 16383]   colsum_part[64 chunks][256]
// [16384]        lossacc  (zeroed by block (0,0) before the grid barrier)
// [16385]        done u32
// [16640 .. ]    partials bf16: NT*CHUNKS*TILE_ELEMS u16 (6.3 MB)
#define WS_LOSS 16384
#define WS_DONE 16385
#define WS_PART 16640

// Grid-barrier arrive counter (device global: ws is re-poisoned every iter).
// Monotonic, +GRID_BLKS per launch; target = next multiple -> no reset needed
// across graph replays.
__device__ unsigned g_bar1 = 0;

__device__ __forceinline__ uint32 pack2bf(float lo, float hi) {
    uint32 a = __float_as_uint(lo), b = __float_as_uint(hi);
    a = (a + 0x7FFFu + ((a >> 16) & 1u)) >> 16;   // RNE fp32->bf16
    b = (b + 0x7FFFu + ((b >> 16) & 1u)) >> 16;
    return (a & 0xFFFFu) | (b << 16);
}
__device__ __forceinline__ u16 f2bf(float x) {
    uint32 a = __float_as_uint(x);
    return (u16)((a + 0x7FFFu + ((a >> 16) & 1u)) >> 16);
}
__device__ __forceinline__ float bflo(uint32 v) { return __uint_as_float(v << 16); }
__device__ __forceinline__ float bfhi(uint32 v) { return __uint_as_float(v & 0xFFFF0000u); }

// LDS layout: U[col][krp] (krp = k/2, 64 dwords per col), 16B-group XOR swizzle.
__device__ __forceinline__ int uswz(int col, int krp) {
    return col * 64 + ((((krp >> 2) ^ (col & 15)) << 2) | (krp & 3));
}

__global__ __launch_bounds__(256)
void corr_fused(const float* __restrict__ E, float* __restrict__ ws,
                float* __restrict__ out) {
    __shared__ uint32 U[WDIM * 64];            // 64 KB
    __shared__ float red[4];
    const int t = blockIdx.x, c = blockIdx.y;
    const int tid = threadIdx.x;
    const int ncg = (t == 1) ? 4 : 2;          // 64-col groups held in U
    const int gcol0 = (t == 2) ? 128 : 0;      // global col of U local col 0
    const int row0 = c * 128;
    const int c4 = tid & 15, rp = tid >> 4;

    // Zero lossacc+done; ordered before all phase-B uses by the grid barrier.
    if (t == 0 && c == 0 && tid < 2) ws[WS_LOSS + tid] = 0.0f;

    // ---------------- phase A: load + cast to LDS ----------------
    for (int cg = 0; cg < ncg; ++cg) {
        const float* Eb = E + (size_t)row0 * WDIM + gcol0 + cg * 64;
        float4 fa[4], fb[4];
        #pragma unroll
        for (int p = 0; p < 4; ++p) {          // rowpairs rp+16p -> rows 2*,2*+1
            const int r0 = 2 * (rp + 16 * p);
            fa[p] = *(const float4*)(Eb + (size_t)r0 * WDIM + c4 * 4);
            fb[p] = *(const float4*)(Eb + (size_t)(r0 + 1) * WDIM + c4 * 4);
        }
        #pragma unroll
        for (int p = 0; p < 4; ++p) {
            const int krp = rp + 16 * p;
            const int colb = cg * 64 + c4 * 4;
            const float av[4] = {fa[p].x, fa[p].y, fa[p].z, fa[p].w};
            const float bv[4] = {fb[p].x, fb[p].y, fb[p].z, fb[p].w};
            #pragma unroll
            for (int i = 0; i < 4; ++i)
                U[uswz(colb + i, krp)] = pack2bf(av[i], bv[i]);
        }
    }
    __syncthreads();

    if (t == 1) {                              // colsum (bf16-rounded; err ~4e-5)
        const int col = tid;                   // all 256 cols live in U here
        float s = 0.f;
        #pragma unroll
        for (int g = 0; g < 16; ++g) {
            const uint4 v = *(const uint4*)&U[col * 64 + ((g ^ (col & 15)) << 2)];
            s += bflo(v.x) + bfhi(v.x) + bflo(v.y) + bfhi(v.y)
               + bflo(v.z) + bfhi(v.z) + bflo(v.w) + bfhi(v.w);
        }
        ws[c * WDIM + col] = s;                // per-chunk slot, no init needed
    }

    // MFMA: wave w -> tile rows [32w,32w+32); local col = global - gcol0.
    const int w = tid >> 6, l = tid & 63, lm = l & 31;
    const int bBase = (t == 1) ? 128 : 0;
    const int colA = w * 32 + lm;

    f32x16 acc[4];
    #pragma unroll
    for (int n = 0; n < 4; ++n)
        #pragma unroll
        for (int r = 0; r < 16; ++r) acc[n][r] = 0.f;

    #pragma unroll
    for (int s8 = 0; s8 < 8; ++s8) {           // K = 128 = 8 steps of 16
        const int grp = 2 * s8 + (l >> 5);     // logical 16B group = k/8
        const bf16x8 a = *(const bf16x8*)&U[colA * 64 + ((grp ^ (colA & 15)) << 2)];
        #pragma unroll
        for (int n = 0; n < 4; ++n) {
            const int colB = bBase + n * 32 + lm;
            const bf16x8 b = *(const bf16x8*)&U[colB * 64 + ((grp ^ (colB & 15)) << 2)];
            acc[n] = __builtin_amdgcn_mfma_f32_32x32x16_bf16(a, b, acc[n], 0, 0, 0);
        }
    }

    // bf16 partials. C/D layout (m74/m101): col = lane&31, row = (r&3)+8*(r>>2)+4*(lane>>5)
    u16* part = (u16*)(ws + WS_PART);
    u16* dst = part + ((size_t)c * NT + t) * TILE_ELEMS;
    const int rbase = 32 * w + 4 * (l >> 5);
    #pragma unroll
    for (int n = 0; n < 4; ++n)
        #pragma unroll
        for (int r = 0; r < 16; ++r) {
            const int row = rbase + (r & 3) + 8 * (r >> 2);
            dst[row * 128 + n * 32 + lm] = f2bf(acc[n][r]);
        }

    // ---------------- device-scope grid barrier (read-poll) ----------------
    // Arrive: ONE device-scope fetch_add per block. Poll: device-scope atomic
    // LOADS only — concurrent L3 reads, no exclusive-line migration (round-1's
    // RMW-poll serialized ~192 RMWs/round and delayed arrivals; cost ~16-24us).
    __syncthreads();                           // all waves' stores issued
    if (tid == 0) {
        __threadfence();                       // release partials/colsums
        const unsigned old = __hip_atomic_fetch_add(
            &g_bar1, 1u, __ATOMIC_ACQ_REL, __HIP_MEMORY_SCOPE_AGENT);
        const unsigned target = old - (old % GRID_BLKS) + GRID_BLKS;
        while (__hip_atomic_load(&g_bar1, __ATOMIC_RELAXED,
                                 __HIP_MEMORY_SCOPE_AGENT) < target)
            __builtin_amdgcn_s_sleep(8);
        __threadfence();                       // acquire
    }
    __syncthreads();

    // ---------------- phase B: finalize loss + sqrt ----------------
    // U is dead past the barrier; alias it for mu[256] and red2[8][256].
    const int b = c * NT + t;                  // flat block id 0..191
    float* muS  = (float*)U;                   // [0..255]
    float* red2 = (float*)U + 256;             // [256..2303]
    const u16* partR = (const u16*)(ws + WS_PART);
    float* lossacc = ws + WS_LOSS;
    unsigned* done = (unsigned*)(ws + WS_DONE);

    {   // reduce the 64 per-chunk colsum slots -> mu
        float s = 0.f;
        #pragma unroll 8
        for (int cc = 0; cc < CHUNKS; ++cc) s += ws[cc * WDIM + tid];
        muS[tid] = s * (1.0f / (float)BROWS);
    }

    // Vectorized partial reduce: lane-group g handles chunks {g, g+8, ...};
    // each lane reads uint4 (8 bf16, 16B) per chunk -> 8 running sums.
    const int e0 = b * 256;                    // block's 256 outputs
    const int tt = e0 >> 14, local0 = e0 & 16383;
    const int gq = tid >> 5, lq = tid & 31;
    float s8v[8] = {0.f, 0.f, 0.f, 0.f, 0.f, 0.f, 0.f, 0.f};
    #pragma unroll
    for (int k = 0; k < 8; ++k) {
        const int cc = gq + 8 * k;
        const uint4 v = *(const uint4*)(partR +
            ((size_t)cc * NT + tt) * TILE_ELEMS + local0 + lq * 8);
        s8v[0] += bflo(v.x); s8v[1] += bfhi(v.x);
        s8v[2] += bflo(v.y); s8v[3] += bfhi(v.y);
        s8v[4] += bflo(v.z); s8v[5] += bfhi(v.z);
        s8v[6] += bflo(v.w); s8v[7] += bfhi(v.w);
    }
    #pragma unroll
    for (int j2 = 0; j2 < 8; ++j2) red2[gq * 256 + lq * 8 + j2] = s8v[j2];
    __syncthreads();

    float gsum = 0.f;
    #pragma unroll
    for (int gg = 0; gg < 8; ++gg) gsum += red2[gg * 256 + tid];

    const int local = local0 + tid;
    const int ti = (tt == 2) ? 1 : 0;
    const int tj = (tt == 0) ? 0 : 1;
    const int i = ti * 128 + (local >> 7);
    const int j = tj * 128 + (local & 127);

    const float diff = gsum * (1.0f / (float)BROWS) - muS[i] * muS[j] - ((i == j) ? 1.0f : 0.0f);
    float v = ((tt == 1) ? 2.0f : 1.0f) * diff * diff;

    #pragma unroll
    for (int o = 32; o > 0; o >>= 1) v += __shfl_down(v, o, 64);
    if ((tid & 63) == 0) red[tid >> 6] = v;
    __syncthreads();
    if (tid == 0) {
        atomicAdd(lossacc, red[0] + red[1] + red[2] + red[3]);
        __threadfence();
        const unsigned fin = atomicAdd(done, 1u);
        if (fin == GRID_BLKS - 1) {
            __threadfence();
            out[0] = sqrtf(atomicAdd(lossacc, 0.0f));  // atomic read
        }
    }
}

// ---------------------------------------------------------------------- host
extern "C" void kernel_launch(void* const* d_in, const int* in_sizes, int n_in,
                              void* d_out, int out_size, void* d_ws, size_t ws_size,
                              hipStream_t stream) {
    const float* E = (const float*)d_in[0];
    // d_in[1] (label) unused by the reference math.
    float* out = (float*)d_out;
    float* ws = (float*)d_ws;

    corr_fused<<<dim3(NT, CHUNKS), 256, 0, stream>>>(E, ws, out);
}